// Round 3
// baseline (188.814 us; speedup 1.0000x reference)
//
#include <hip/hip_runtime.h>
#include <hip/hip_bf16.h>

typedef __hip_bfloat16 bf16;
typedef __attribute__((ext_vector_type(8))) short short8;
typedef __attribute__((ext_vector_type(4))) short short4v;
typedef __attribute__((ext_vector_type(4))) float f32x4;
typedef __attribute__((ext_vector_type(4))) float float4v;

static __device__ inline short f2bf(float f){
  __hip_bfloat16 h = __float2bfloat16(f);
  return *reinterpret_cast<short*>(&h);
}

static __device__ inline short8 load8(const float* p){
  float4v a = *reinterpret_cast<const float4v*>(p);
  float4v b = *reinterpret_cast<const float4v*>(p + 4);
  short8 r;
  r[0]=f2bf(a[0]); r[1]=f2bf(a[1]); r[2]=f2bf(a[2]); r[3]=f2bf(a[3]);
  r[4]=f2bf(b[0]); r[5]=f2bf(b[1]); r[6]=f2bf(b[2]); r[7]=f2bf(b[3]);
  return r;
}
static __device__ inline short8 load8(const bf16* p){
  return *reinterpret_cast<const short8*>(p);
}

// cos/sin table: tab[s*32+d] = {cos, sin} of s * 10000^(-d/32)
__global__ void rope_table_kernel(float* __restrict__ tab){
  const int idx = blockIdx.x * 256 + threadIdx.x;   // 2048*32
  const int d = idx & 31, s = idx >> 5;
  const float ang = (float)s * exp2f(-0.41524101186092030f * (float)d);
  float sn, cs;
  sincosf(ang, &sn, &cs);
  tab[idx*2] = cs; tab[idx*2+1] = sn;
}

// Shared GEMM body: C = A[M,K] @ B[N,K]^T + bias, epilogue by MODE.
// MODE 0: fp32 C[M,N].  MODE 1: rope*SC -> Qa bf16 [B*16,2048,64].
// MODE 2: rope -> Ka bf16 [B*4,2048,64].  MODE 3: V^T bf16 [B*4,64,2048].
template<int MODE, typename TA>
__device__ __forceinline__ void gemm_bt_body(
    short* As, short* Bs, void* __restrict__ Cout,
    const TA* __restrict__ A, const float* __restrict__ B,
    const float* __restrict__ bias, const float* __restrict__ tab,
    int M, int N, int K)
{
  constexpr int BK = 32, LDT = 40;  // 80B rows: 16B aligned, 2-way banks (free)
  const int n0 = blockIdx.x * 128, m0 = blockIdx.y * 128;
  const int tid = threadIdx.x;
  const int w = tid >> 6, lane = tid & 63;
  const int wm = w >> 1, wn = w & 1;
  const int lr = lane & 15, lk = (lane >> 4) * 8;
  f32x4 acc[4][4] = {};
  for (int k0 = 0; k0 < K; k0 += BK){
    __syncthreads();
    {
      const int r = tid >> 2, c8 = (tid & 3) * 8;
      *reinterpret_cast<short8*>(&As[ r      * LDT + c8]) = load8(A + (size_t)(m0 + r     ) * K + k0 + c8);
      *reinterpret_cast<short8*>(&As[(r + 64)* LDT + c8]) = load8(A + (size_t)(m0 + r + 64) * K + k0 + c8);
      *reinterpret_cast<short8*>(&Bs[ r      * LDT + c8]) = load8(B + (size_t)(n0 + r     ) * K + k0 + c8);
      *reinterpret_cast<short8*>(&Bs[(r + 64)* LDT + c8]) = load8(B + (size_t)(n0 + r + 64) * K + k0 + c8);
    }
    __syncthreads();
    short8 af[4], bfm[4];
    #pragma unroll
    for (int mt = 0; mt < 4; mt++)
      af[mt] = *reinterpret_cast<short8*>(&As[(wm*64 + mt*16 + lr) * LDT + lk]);
    #pragma unroll
    for (int nt = 0; nt < 4; nt++)
      bfm[nt] = *reinterpret_cast<short8*>(&Bs[(wn*64 + nt*16 + lr) * LDT + lk]);
    #pragma unroll
    for (int mt = 0; mt < 4; mt++)
      #pragma unroll
      for (int nt = 0; nt < 4; nt++)
        acc[mt][nt] = __builtin_amdgcn_mfma_f32_16x16x32_bf16(af[mt], bfm[nt], acc[mt][nt], 0, 0, 0);
  }
  const int lg = lane >> 4;
  if constexpr (MODE == 0){
    float* C = (float*)Cout;
    #pragma unroll
    for (int mt = 0; mt < 4; mt++){
      #pragma unroll
      for (int nt = 0; nt < 4; nt++){
        const int col = n0 + wn*64 + nt*16 + lr;
        const float bv = bias[col];
        const int rbase = m0 + wm*64 + mt*16 + lg*4;
        #pragma unroll
        for (int i = 0; i < 4; i++)
          C[(size_t)(rbase + i) * N + col] = acc[mt][nt][i] + bv;
      }
    }
  } else if constexpr (MODE == 1 || MODE == 2){
    bf16* dst = (bf16*)Cout;
    constexpr int NH = (MODE == 1) ? 16 : 4;
    // SC folds attention scale + log2(e) into Q so softmax runs in exp2 domain
    constexpr float SC = (MODE == 1) ? 0.18033688011112042f : 1.0f;
    #pragma unroll
    for (int mt = 0; mt < 4; mt++){
      #pragma unroll
      for (int nt = 0; nt < 2; nt++){
        const int col = n0 + wn*64 + nt*16 + lr;
        const int d = col & 63;        // 0..31
        const int hh = col >> 6;
        const float b1 = bias[col], b2 = bias[col + 32];
        #pragma unroll
        for (int i = 0; i < 4; i++){
          const int m = m0 + wm*64 + mt*16 + lg*4 + i;
          const int s = m & 2047, bb = m >> 11;
          const float cs = tab[(s*32 + d)*2], sn = tab[(s*32 + d)*2 + 1];
          const float x1 = acc[mt][nt][i] + b1;
          const float x2 = acc[mt][nt+2][i] + b2;
          const size_t o = ((size_t)(bb*NH + hh) * 2048 + s) * 64 + d;
          dst[o]      = __float2bfloat16((x1*cs - x2*sn) * SC);
          dst[o + 32] = __float2bfloat16((x2*cs + x1*sn) * SC);
        }
      }
    }
  } else {  // MODE 3: V^T
    bf16* dst = (bf16*)Cout;
    #pragma unroll
    for (int mt = 0; mt < 4; mt++){
      #pragma unroll
      for (int nt = 0; nt < 4; nt++){
        const int col = n0 + wn*64 + nt*16 + lr;
        const int kv = col >> 6, d = col & 63;
        const float bv = bias[col];
        #pragma unroll
        for (int i = 0; i < 4; i++){
          const int m = m0 + wm*64 + mt*16 + lg*4 + i;
          const int s = m & 2047, bb = m >> 11;
          dst[((size_t)(bb*4 + kv) * 64 + d) * 2048 + s] = __float2bfloat16(acc[mt][nt][i] + bv);
        }
      }
    }
  }
}

__global__ __launch_bounds__(256) void gemm_q_kernel(
    bf16* Qa, const float* A, const float* B, const float* bias, const float* tab){
  __shared__ short As[128*40], Bs[128*40];
  gemm_bt_body<1, float>(As, Bs, Qa, A, B, bias, tab, 4096, 1024, 1024);
}
__global__ __launch_bounds__(256) void gemm_kv_kernel(
    bf16* Ka, bf16* Va, const float* key, const float* value,
    const float* Wk, const float* bk, const float* Wv, const float* bv,
    const float* tab){
  __shared__ short As[128*40], Bs[128*40];
  if (blockIdx.z == 0)
    gemm_bt_body<2, float>(As, Bs, Ka, key, Wk, bk, tab, 4096, 256, 1024);
  else
    gemm_bt_body<3, float>(As, Bs, Va, value, Wv, bv, tab, 4096, 256, 1024);
}
__global__ __launch_bounds__(256) void gemm_out_kernel(
    float* C, const bf16* A, const float* B, const float* bias){
  __shared__ short As[128*40], Bs[128*40];
  gemm_bt_body<0, bf16>(As, Bs, C, A, B, bias, nullptr, 4096, 1024, 1024);
}

// Flash attention v3: grid (16, 32); 4 waves, 32 q-rows/wave, KV tiles of 64.
// Swapped QK^T; double-buffered swizzled K/V LDS; ONE barrier per tile;
// base-2 deferred-max softmax (Q pre-scaled by 0.125*log2e in projection).
__global__ __launch_bounds__(256) void attn_kernel(
    bf16* __restrict__ ctx, const bf16* __restrict__ Qa,
    const bf16* __restrict__ Ka, const bf16* __restrict__ Vt)
{
  constexpr int DK = 64, KVB = 64, LDP = 72;
  __shared__ short Klds[2][KVB * 64];
  __shared__ short Vlds[2][DK * 64];
  __shared__ short Plds[4 * 32 * LDP];  // per-wave P[q][kv]
  const int bh = blockIdx.y, b = bh >> 4, h = bh & 15, kvh = h >> 2;
  const int q0 = blockIdx.x * 128;
  const int tid = threadIdx.x, w = tid >> 6, lane = tid & 63;
  const int lr = lane & 15, lg = lane >> 4;
  const bf16* Qbase = Qa + (size_t)bh * 2048 * DK;
  const bf16* Kbase = Ka + (size_t)(b*4 + kvh) * 2048 * DK;
  const bf16* Vbase = Vt + (size_t)(b*4 + kvh) * DK * 2048;

  short8 qf[2][2];
  #pragma unroll
  for (int qt = 0; qt < 2; qt++)
    #pragma unroll
    for (int kk = 0; kk < 2; kk++)
      qf[qt][kk] = *reinterpret_cast<const short8*>(
          Qbase + (size_t)(q0 + w*32 + qt*16 + lr) * DK + kk*32 + lg*8);

  float mrow[2] = {-1e30f, -1e30f}, lsum[2] = {0.f, 0.f};
  f32x4 o[2][4] = {};

  const int srow = tid >> 2;          // 0..63
  const int sc = (tid & 3) * 16;      // element col {0,16,32,48}
  short8 kreg[2], vreg[2];
  auto loadKV = [&](int kt){
    const bf16* p = Kbase + (size_t)(kt + srow) * DK + sc;
    kreg[0] = load8(p); kreg[1] = load8(p + 8);
    const bf16* q = Vbase + (size_t)srow * 2048 + kt + sc;
    vreg[0] = load8(q); vreg[1] = load8(q + 8);
  };
  loadKV(0);

  // XOR swizzle: row-major [64][64] bf16 (128B rows), byte ^= (row&7)<<4.
  auto swz = [](int row, int col) -> int {
    return ((row << 7) + (col << 1)) ^ ((row & 7) << 4);
  };

  char* Kb0 = (char*)&Klds[0][0];
  char* Vb0 = (char*)&Vlds[0][0];
  short* Pw = &Plds[w * 32 * LDP];

  for (int t = 0; t < 32; t++){
    char* Kc = Kb0 + (t & 1) * (KVB * 64 * 2);
    char* Vc = Vb0 + (t & 1) * (DK * 64 * 2);
    *reinterpret_cast<short8*>(Kc + swz(srow, sc))     = kreg[0];
    *reinterpret_cast<short8*>(Kc + swz(srow, sc + 8)) = kreg[1];
    *reinterpret_cast<short8*>(Vc + swz(srow, sc))     = vreg[0];
    *reinterpret_cast<short8*>(Vc + swz(srow, sc + 8)) = vreg[1];
    __syncthreads();
    if (t < 31) loadKV((t + 1) * KVB);   // issue next tile's loads now

    // S^T = K x Q : lane holds S2[kv=mt*16+lg*4+i][q=qt*16+lr] (exp2 domain)
    f32x4 st[4][2] = {};
    __builtin_amdgcn_s_setprio(1);
    #pragma unroll
    for (int mt = 0; mt < 4; mt++){
      #pragma unroll
      for (int kk = 0; kk < 2; kk++){
        short8 kf = *reinterpret_cast<const short8*>(Kc + swz(mt*16 + lr, kk*32 + lg*8));
        #pragma unroll
        for (int qt = 0; qt < 2; qt++)
          st[mt][qt] = __builtin_amdgcn_mfma_f32_16x16x32_bf16(kf, qf[qt][kk], st[mt][qt], 0, 0, 0);
      }
    }
    __builtin_amdgcn_s_setprio(0);

    #pragma unroll
    for (int qt = 0; qt < 2; qt++){
      float mx = fmaxf(fmaxf(fmaxf(st[0][qt][0], st[0][qt][1]), fmaxf(st[0][qt][2], st[0][qt][3])),
                       fmaxf(fmaxf(st[1][qt][0], st[1][qt][1]), fmaxf(st[1][qt][2], st[1][qt][3])));
      mx = fmaxf(mx, fmaxf(fmaxf(fmaxf(st[2][qt][0], st[2][qt][1]), fmaxf(st[2][qt][2], st[2][qt][3])),
                           fmaxf(fmaxf(st[3][qt][0], st[3][qt][1]), fmaxf(st[3][qt][2], st[3][qt][3]))));
      mx = fmaxf(mx, __shfl_xor(mx, 16));
      mx = fmaxf(mx, __shfl_xor(mx, 32));
      // T13 defer-max: only rescale when the new max exceeds budget (P <= 2^8)
      if (__any(mx > mrow[qt] + 8.0f)){
        const float nm = fmaxf(mrow[qt], mx);
        const float alpha = exp2f(mrow[qt] - nm);
        mrow[qt] = nm;
        lsum[qt] *= alpha;
        float ab[4];
        #pragma unroll
        for (int i = 0; i < 4; i++) ab[i] = __shfl(alpha, lg*4 + i);
        #pragma unroll
        for (int dt = 0; dt < 4; dt++)
          #pragma unroll
          for (int i = 0; i < 4; i++)
            o[qt][dt][i] *= ab[i];
      }
      float s = 0.f;
      #pragma unroll
      for (int mt = 0; mt < 4; mt++){
        short4v pb;
        #pragma unroll
        for (int i = 0; i < 4; i++){
          const float e = exp2f(st[mt][qt][i] - mrow[qt]);
          s += e;
          pb[i] = f2bf(e);
        }
        *reinterpret_cast<short4v*>(&Pw[(qt*16 + lr)*LDP + mt*16 + lg*4]) = pb;
      }
      s += __shfl_xor(s, 16);
      s += __shfl_xor(s, 32);
      lsum[qt] += s;
    }

    asm volatile("s_waitcnt lgkmcnt(0)" ::: "memory");
    __builtin_amdgcn_sched_barrier(0);
    short8 pf[2][2];
    #pragma unroll
    for (int qt = 0; qt < 2; qt++)
      #pragma unroll
      for (int kk = 0; kk < 2; kk++)
        pf[qt][kk] = *reinterpret_cast<const short8*>(&Pw[(qt*16 + lr)*LDP + kk*32 + lg*8]);
    __builtin_amdgcn_s_setprio(1);
    #pragma unroll
    for (int dt = 0; dt < 4; dt++){
      #pragma unroll
      for (int kk = 0; kk < 2; kk++){
        short8 vf = *reinterpret_cast<const short8*>(Vc + swz(dt*16 + lr, kk*32 + lg*8));
        #pragma unroll
        for (int qt = 0; qt < 2; qt++)
          o[qt][dt] = __builtin_amdgcn_mfma_f32_16x16x32_bf16(pf[qt][kk], vf, o[qt][dt], 0, 0, 0);
      }
    }
    __builtin_amdgcn_s_setprio(0);
  }

  #pragma unroll
  for (int qt = 0; qt < 2; qt++){
    float lb[4];
    #pragma unroll
    for (int i = 0; i < 4; i++) lb[i] = 1.0f / __shfl(lsum[qt], lg*4 + i);
    #pragma unroll
    for (int dt = 0; dt < 4; dt++){
      #pragma unroll
      for (int i = 0; i < 4; i++){
        const int q = q0 + w*32 + qt*16 + lg*4 + i;
        ctx[(size_t)(b*2048 + q) * 1024 + h*64 + dt*16 + lr] =
            __float2bfloat16(o[qt][dt][i] * lb[i]);
      }
    }
  }
}

extern "C" void kernel_launch(void* const* d_in, const int* in_sizes, int n_in,
                              void* d_out, int out_size, void* d_ws, size_t ws_size,
                              hipStream_t stream)
{
  const float* query = (const float*)d_in[0];
  const float* key   = (const float*)d_in[1];
  const float* value = (const float*)d_in[2];
  const float* Wq = (const float*)d_in[3];
  const float* bq = (const float*)d_in[4];
  const float* Wk = (const float*)d_in[5];
  const float* bk = (const float*)d_in[6];
  const float* Wv = (const float*)d_in[7];
  const float* bv = (const float*)d_in[8];
  const float* Wo = (const float*)d_in[9];
  const float* bo = (const float*)d_in[10];
  float* out = (float*)d_out;

  char* ws = (char*)d_ws;
  size_t off = 0;
  float* tab = (float*)(ws + off); off += (size_t)2048 * 32 * 2 * 4;   // cos/sin
  bf16*  Qa  = (bf16*)(ws + off);  off += (size_t)32 * 2048 * 64 * 2;  // [B*16,S,64]
  bf16*  Ka  = (bf16*)(ws + off);  off += (size_t)8 * 2048 * 64 * 2;   // [B*4,S,64]
  bf16*  Va  = (bf16*)(ws + off);  off += (size_t)8 * 64 * 2048 * 2;   // [B*4,64,S]
  bf16*  ctx = (bf16*)(ws + off);  off += (size_t)2 * 2048 * 1024 * 2; // [B,S,1024]

  rope_table_kernel<<<256, 256, 0, stream>>>(tab);
  gemm_q_kernel<<<dim3(8, 32), 256, 0, stream>>>(Qa, query, Wq, bq, tab);
  gemm_kv_kernel<<<dim3(2, 32, 2), 256, 0, stream>>>(Ka, Va, key, value, Wk, bk, Wv, bv, tab);
  attn_kernel<<<dim3(16, 32), 256, 0, stream>>>(ctx, Qa, Ka, Va);
  gemm_out_kernel<<<dim3(8, 32), 256, 0, stream>>>(out, ctx, Wo, bo);
}

// Round 4
// 168.009 us; speedup vs baseline: 1.1238x; 1.1238x over previous
//
#include <hip/hip_runtime.h>
#include <hip/hip_bf16.h>

typedef __hip_bfloat16 bf16;
typedef __attribute__((ext_vector_type(8))) short short8;
typedef __attribute__((ext_vector_type(4))) short short4v;
typedef __attribute__((ext_vector_type(4))) float f32x4;
typedef __attribute__((ext_vector_type(4))) float float4v;

static __device__ inline short f2bf(float f){
  __hip_bfloat16 h = __float2bfloat16(f);
  return *reinterpret_cast<short*>(&h);
}

static __device__ inline short8 load8(const float* p){
  float4v a = *reinterpret_cast<const float4v*>(p);
  float4v b = *reinterpret_cast<const float4v*>(p + 4);
  short8 r;
  r[0]=f2bf(a[0]); r[1]=f2bf(a[1]); r[2]=f2bf(a[2]); r[3]=f2bf(a[3]);
  r[4]=f2bf(b[0]); r[5]=f2bf(b[1]); r[6]=f2bf(b[2]); r[7]=f2bf(b[3]);
  return r;
}
static __device__ inline short8 load8(const bf16* p){
  return *reinterpret_cast<const short8*>(p);
}

// cos/sin table: tab[s*32+d] = {cos, sin} of s * 10000^(-d/32)
__global__ void rope_table_kernel(float* __restrict__ tab){
  const int idx = blockIdx.x * 256 + threadIdx.x;   // 2048*32
  const int d = idx & 31, s = idx >> 5;
  const float ang = (float)s * exp2f(-0.41524101186092030f * (float)d);
  float sn, cs;
  sincosf(ang, &sn, &cs);
  tab[idx*2] = cs; tab[idx*2+1] = sn;
}

// Shared GEMM body: C = A[M,K] @ B[N,K]^T + bias, epilogue by MODE.
// MODE 0: fp32 C[M,N].  MODE 1: rope*SC -> Qa bf16 [B*16,2048,64].
// MODE 2: rope -> Ka bf16 [B*4,2048,64].  MODE 3: V^T bf16 [B*4,64,2048].
template<int MODE, typename TA>
__device__ __forceinline__ void gemm_bt_body(
    short* As, short* Bs, void* __restrict__ Cout,
    const TA* __restrict__ A, const float* __restrict__ B,
    const float* __restrict__ bias, const float* __restrict__ tab,
    int ntile, int M, int N, int K)
{
  constexpr int BK = 32, LDT = 40;  // 80B rows: 16B aligned, 2-way banks (free)
  const int n0 = ntile * 128, m0 = blockIdx.y * 128;
  const int tid = threadIdx.x;
  const int w = tid >> 6, lane = tid & 63;
  const int wm = w >> 1, wn = w & 1;
  const int lr = lane & 15, lk = (lane >> 4) * 8;
  f32x4 acc[4][4] = {};
  for (int k0 = 0; k0 < K; k0 += BK){
    __syncthreads();
    {
      const int r = tid >> 2, c8 = (tid & 3) * 8;
      *reinterpret_cast<short8*>(&As[ r      * LDT + c8]) = load8(A + (size_t)(m0 + r     ) * K + k0 + c8);
      *reinterpret_cast<short8*>(&As[(r + 64)* LDT + c8]) = load8(A + (size_t)(m0 + r + 64) * K + k0 + c8);
      *reinterpret_cast<short8*>(&Bs[ r      * LDT + c8]) = load8(B + (size_t)(n0 + r     ) * K + k0 + c8);
      *reinterpret_cast<short8*>(&Bs[(r + 64)* LDT + c8]) = load8(B + (size_t)(n0 + r + 64) * K + k0 + c8);
    }
    __syncthreads();
    short8 af[4], bfm[4];
    #pragma unroll
    for (int mt = 0; mt < 4; mt++)
      af[mt] = *reinterpret_cast<short8*>(&As[(wm*64 + mt*16 + lr) * LDT + lk]);
    #pragma unroll
    for (int nt = 0; nt < 4; nt++)
      bfm[nt] = *reinterpret_cast<short8*>(&Bs[(wn*64 + nt*16 + lr) * LDT + lk]);
    #pragma unroll
    for (int mt = 0; mt < 4; mt++)
      #pragma unroll
      for (int nt = 0; nt < 4; nt++)
        acc[mt][nt] = __builtin_amdgcn_mfma_f32_16x16x32_bf16(af[mt], bfm[nt], acc[mt][nt], 0, 0, 0);
  }
  const int lg = lane >> 4;
  if constexpr (MODE == 0){
    float* C = (float*)Cout;
    #pragma unroll
    for (int mt = 0; mt < 4; mt++){
      #pragma unroll
      for (int nt = 0; nt < 4; nt++){
        const int col = n0 + wn*64 + nt*16 + lr;
        const float bv = bias[col];
        const int rbase = m0 + wm*64 + mt*16 + lg*4;
        #pragma unroll
        for (int i = 0; i < 4; i++)
          C[(size_t)(rbase + i) * N + col] = acc[mt][nt][i] + bv;
      }
    }
  } else if constexpr (MODE == 1 || MODE == 2){
    bf16* dst = (bf16*)Cout;
    constexpr int NH = (MODE == 1) ? 16 : 4;
    // SC folds attention scale + log2(e) into Q so softmax runs in exp2 domain
    constexpr float SC = (MODE == 1) ? 0.18033688011112042f : 1.0f;
    #pragma unroll
    for (int mt = 0; mt < 4; mt++){
      #pragma unroll
      for (int nt = 0; nt < 2; nt++){
        const int col = n0 + wn*64 + nt*16 + lr;
        const int d = col & 63;        // 0..31
        const int hh = col >> 6;
        const float b1 = bias[col], b2 = bias[col + 32];
        #pragma unroll
        for (int i = 0; i < 4; i++){
          const int m = m0 + wm*64 + mt*16 + lg*4 + i;
          const int s = m & 2047, bb = m >> 11;
          const float cs = tab[(s*32 + d)*2], sn = tab[(s*32 + d)*2 + 1];
          const float x1 = acc[mt][nt][i] + b1;
          const float x2 = acc[mt][nt+2][i] + b2;
          const size_t o = ((size_t)(bb*NH + hh) * 2048 + s) * 64 + d;
          dst[o]      = __float2bfloat16((x1*cs - x2*sn) * SC);
          dst[o + 32] = __float2bfloat16((x2*cs + x1*sn) * SC);
        }
      }
    }
  } else {  // MODE 3: V^T
    bf16* dst = (bf16*)Cout;
    #pragma unroll
    for (int mt = 0; mt < 4; mt++){
      #pragma unroll
      for (int nt = 0; nt < 4; nt++){
        const int col = n0 + wn*64 + nt*16 + lr;
        const int kv = col >> 6, d = col & 63;
        const float bv = bias[col];
        #pragma unroll
        for (int i = 0; i < 4; i++){
          const int m = m0 + wm*64 + mt*16 + lg*4 + i;
          const int s = m & 2047, bb = m >> 11;
          dst[((size_t)(bb*4 + kv) * 64 + d) * 2048 + s] = __float2bfloat16(acc[mt][nt][i] + bv);
        }
      }
    }
  }
}

// Merged QKV projection: x 0-7 Q tiles, 8-9 K tiles, 10-11 V tiles.
__global__ __launch_bounds__(256) void gemm_qkv_kernel(
    bf16* Qa, bf16* Ka, bf16* Va,
    const float* query, const float* key, const float* value,
    const float* Wq, const float* bq, const float* Wk, const float* bk,
    const float* Wv, const float* bv, const float* tab){
  __shared__ short As[128*40], Bs[128*40];
  const int x = blockIdx.x;
  if (x < 8)
    gemm_bt_body<1, float>(As, Bs, Qa, query, Wq, bq, tab, x,    4096, 1024, 1024);
  else if (x < 10)
    gemm_bt_body<2, float>(As, Bs, Ka, key,   Wk, bk, tab, x-8,  4096, 256, 1024);
  else
    gemm_bt_body<3, float>(As, Bs, Va, value, Wv, bv, tab, x-10, 4096, 256, 1024);
}
__global__ __launch_bounds__(256) void gemm_out_kernel(
    float* C, const bf16* A, const float* B, const float* bias){
  __shared__ short As[128*40], Bs[128*40];
  gemm_bt_body<0, bf16>(As, Bs, C, A, B, bias, nullptr, blockIdx.x, 4096, 1024, 1024);
}

// Flash attention v4: grid (32, 32); 4 waves x 16 q-rows, KV tiles of 64.
// Swapped QK^T; P stays in REGISTERS (permuted-k MFMA: V B-frag read as two
// b64s at matching permuted columns); double-buffered swizzled K/V LDS;
// one barrier/tile; base-2 deferred-max softmax.
__global__ __launch_bounds__(256) void attn_kernel(
    bf16* __restrict__ ctx, const bf16* __restrict__ Qa,
    const bf16* __restrict__ Ka, const bf16* __restrict__ Vt)
{
  constexpr int KVB = 64;
  __shared__ short Klds[2][KVB * 64];
  __shared__ short Vlds[2][64 * 64];
  const int bh = blockIdx.y, b = bh >> 4, h = bh & 15, kvh = h >> 2;
  const int q0 = blockIdx.x * 64;
  const int tid = threadIdx.x, w = tid >> 6, lane = tid & 63;
  const int lr = lane & 15, lg = lane >> 4;
  const bf16* Qbase = Qa + (size_t)bh * 2048 * 64;
  const bf16* Kbase = Ka + (size_t)(b*4 + kvh) * 2048 * 64;
  const bf16* Vbase = Vt + (size_t)(b*4 + kvh) * 64 * 2048;

  short8 qf[2];
  qf[0] = load8(Qbase + (size_t)(q0 + w*16 + lr) * 64 + lg*8);
  qf[1] = load8(Qbase + (size_t)(q0 + w*16 + lr) * 64 + 32 + lg*8);

  float mrow = -1e30f, lsum = 0.f;
  f32x4 o[4] = {};

  const int srow = tid >> 2;          // 0..63
  const int sc = (tid & 3) * 16;      // element col {0,16,32,48}
  short8 kreg[2], vreg[2];
  auto loadKV = [&](int kt){
    const bf16* p = Kbase + (size_t)(kt + srow) * 64 + sc;
    kreg[0] = load8(p); kreg[1] = load8(p + 8);
    const bf16* q = Vbase + (size_t)srow * 2048 + kt + sc;
    vreg[0] = load8(q); vreg[1] = load8(q + 8);
  };
  loadKV(0);

  // byte-offset swizzle for row-major [64][64] bf16 (128B rows)
  auto swzb = [](int row, int cb) -> int { return row*128 + (cb ^ ((row & 7) << 4)); };

  for (int t = 0; t < 32; t++){
    char* Kc = (char*)&Klds[t & 1][0];
    char* Vc = (char*)&Vlds[t & 1][0];
    *reinterpret_cast<short8*>(Kc + swzb(srow, sc*2))      = kreg[0];
    *reinterpret_cast<short8*>(Kc + swzb(srow, sc*2 + 16)) = kreg[1];
    *reinterpret_cast<short8*>(Vc + swzb(srow, sc*2))      = vreg[0];
    *reinterpret_cast<short8*>(Vc + swzb(srow, sc*2 + 16)) = vreg[1];
    __syncthreads();
    if (t < 31) loadKV((t + 1) * KVB);   // issue next tile's loads now

    // S^T = K x Q : lane holds S2[kv=mt*16+lg*4+i][q=lr] (exp2 domain)
    f32x4 st[4] = {};
    __builtin_amdgcn_s_setprio(1);
    #pragma unroll
    for (int mt = 0; mt < 4; mt++){
      #pragma unroll
      for (int kk = 0; kk < 2; kk++){
        short8 kf = *reinterpret_cast<const short8*>(Kc + swzb(mt*16 + lr, kk*64 + lg*16));
        st[mt] = __builtin_amdgcn_mfma_f32_16x16x32_bf16(kf, qf[kk], st[mt], 0, 0, 0);
      }
    }
    __builtin_amdgcn_s_setprio(0);

    float mx = -1e30f;
    #pragma unroll
    for (int mt = 0; mt < 4; mt++)
      #pragma unroll
      for (int i = 0; i < 4; i++)
        mx = fmaxf(mx, st[mt][i]);
    mx = fmaxf(mx, __shfl_xor(mx, 16));
    mx = fmaxf(mx, __shfl_xor(mx, 32));
    // T13 defer-max: rescale only when new max exceeds budget (P <= 2^8)
    if (__any(mx > mrow + 8.0f)){
      const float nm = fmaxf(mrow, mx);
      const float alpha = exp2f(mrow - nm);
      mrow = nm;
      lsum *= alpha;
      float ab[4];
      #pragma unroll
      for (int i = 0; i < 4; i++) ab[i] = __shfl(alpha, lg*4 + i);
      #pragma unroll
      for (int dt = 0; dt < 4; dt++)
        #pragma unroll
        for (int i = 0; i < 4; i++)
          o[dt][i] *= ab[i];
    }
    // P in registers, packed in natural slot order (defines k-permutation):
    // pf[kkA] slot j holds P[q=lr][kv = 32*kkA + 16*(j>>2) + 4*lg + (j&3)]
    short8 pf[2];
    float s = 0.f;
    #pragma unroll
    for (int mt = 0; mt < 4; mt++)
      #pragma unroll
      for (int i = 0; i < 4; i++){
        const float e = exp2f(st[mt][i] - mrow);
        s += e;
        pf[mt >> 1][(mt & 1)*4 + i] = f2bf(e);
      }
    s += __shfl_xor(s, 16);
    s += __shfl_xor(s, 32);
    lsum += s;

    // PV with matching permuted V B-frag: slot j needs V^T[d][32kkA+16(j>>2)+4lg+(j&3)]
    // = two 4-element runs -> two ds_read_b64 at element cols 32kkA+4lg and +16.
    __builtin_amdgcn_s_setprio(1);
    #pragma unroll
    for (int dt = 0; dt < 4; dt++){
      #pragma unroll
      for (int kkA = 0; kkA < 2; kkA++){
        const int vrow = dt*16 + lr;
        short4v vlo = *reinterpret_cast<const short4v*>(Vc + swzb(vrow, kkA*64 + lg*8));
        short4v vhi = *reinterpret_cast<const short4v*>(Vc + swzb(vrow, kkA*64 + lg*8 + 32));
        short8 vf;
        vf[0]=vlo[0]; vf[1]=vlo[1]; vf[2]=vlo[2]; vf[3]=vlo[3];
        vf[4]=vhi[0]; vf[5]=vhi[1]; vf[6]=vhi[2]; vf[7]=vhi[3];
        o[dt] = __builtin_amdgcn_mfma_f32_16x16x32_bf16(pf[kkA], vf, o[dt], 0, 0, 0);
      }
    }
    __builtin_amdgcn_s_setprio(0);
  }

  float lb[4];
  #pragma unroll
  for (int i = 0; i < 4; i++) lb[i] = 1.0f / __shfl(lsum, lg*4 + i);
  #pragma unroll
  for (int dt = 0; dt < 4; dt++){
    #pragma unroll
    for (int i = 0; i < 4; i++){
      const int q = q0 + w*16 + lg*4 + i;
      ctx[(size_t)(b*2048 + q) * 1024 + h*64 + dt*16 + lr] =
          __float2bfloat16(o[dt][i] * lb[i]);
    }
  }
}

extern "C" void kernel_launch(void* const* d_in, const int* in_sizes, int n_in,
                              void* d_out, int out_size, void* d_ws, size_t ws_size,
                              hipStream_t stream)
{
  const float* query = (const float*)d_in[0];
  const float* key   = (const float*)d_in[1];
  const float* value = (const float*)d_in[2];
  const float* Wq = (const float*)d_in[3];
  const float* bq = (const float*)d_in[4];
  const float* Wk = (const float*)d_in[5];
  const float* bk = (const float*)d_in[6];
  const float* Wv = (const float*)d_in[7];
  const float* bv = (const float*)d_in[8];
  const float* Wo = (const float*)d_in[9];
  const float* bo = (const float*)d_in[10];
  float* out = (float*)d_out;

  char* ws = (char*)d_ws;
  size_t off = 0;
  float* tab = (float*)(ws + off); off += (size_t)2048 * 32 * 2 * 4;   // cos/sin
  bf16*  Qa  = (bf16*)(ws + off);  off += (size_t)32 * 2048 * 64 * 2;  // [B*16,S,64]
  bf16*  Ka  = (bf16*)(ws + off);  off += (size_t)8 * 2048 * 64 * 2;   // [B*4,S,64]
  bf16*  Va  = (bf16*)(ws + off);  off += (size_t)8 * 64 * 2048 * 2;   // [B*4,64,S]
  bf16*  ctx = (bf16*)(ws + off);  off += (size_t)2 * 2048 * 1024 * 2; // [B,S,1024]

  rope_table_kernel<<<256, 256, 0, stream>>>(tab);
  gemm_qkv_kernel<<<dim3(12, 32), 256, 0, stream>>>(Qa, Ka, Va, query, key, value,
                                                    Wq, bq, Wk, bk, Wv, bv, tab);
  attn_kernel<<<dim3(32, 32), 256, 0, stream>>>(ctx, Qa, Ka, Va);
  gemm_out_kernel<<<dim3(8, 32), 256, 0, stream>>>(out, ctx, Wo, bo);
}

// Round 5
// 157.032 us; speedup vs baseline: 1.2024x; 1.0699x over previous
//
#include <hip/hip_runtime.h>
#include <hip/hip_bf16.h>

typedef __hip_bfloat16 bf16;
typedef __attribute__((ext_vector_type(8))) short short8;
typedef __attribute__((ext_vector_type(4))) short short4v;
typedef __attribute__((ext_vector_type(4))) float f32x4;
typedef __attribute__((ext_vector_type(4))) float float4v;

static __device__ inline short f2bf(float f){
  __hip_bfloat16 h = __float2bfloat16(f);
  return *reinterpret_cast<short*>(&h);
}

static __device__ inline short8 load8(const float* p){
  float4v a = *reinterpret_cast<const float4v*>(p);
  float4v b = *reinterpret_cast<const float4v*>(p + 4);
  short8 r;
  r[0]=f2bf(a[0]); r[1]=f2bf(a[1]); r[2]=f2bf(a[2]); r[3]=f2bf(a[3]);
  r[4]=f2bf(b[0]); r[5]=f2bf(b[1]); r[6]=f2bf(b[2]); r[7]=f2bf(b[3]);
  return r;
}
static __device__ inline short8 load8(const bf16* p){
  return *reinterpret_cast<const short8*>(p);
}

// async global -> LDS DMA, 16B per lane: lane i lands at lds + i*16B (linear)
typedef __attribute__((address_space(1))) const unsigned int gas_u32;
typedef __attribute__((address_space(3))) unsigned int las_u32;
static __device__ __forceinline__ void gload16(const void* g, void* l){
  __builtin_amdgcn_global_load_lds((gas_u32*)g, (las_u32*)l, 16, 0, 0);
}

// cos/sin table: tab[s*32+d] = {cos, sin} of s * 10000^(-d/32)
__global__ void rope_table_kernel(float* __restrict__ tab){
  const int idx = blockIdx.x * 256 + threadIdx.x;   // 2048*32
  const int d = idx & 31, s = idx >> 5;
  const float ang = (float)s * exp2f(-0.41524101186092030f * (float)d);
  float sn, cs;
  sincosf(ang, &sn, &cs);
  tab[idx*2] = cs; tab[idx*2+1] = sn;
}

// Shared GEMM body: C = A[M,K] @ B[N,K]^T + bias, epilogue by MODE.
// MODE 0: fp32 C[M,N].  MODE 1: rope*SC -> Qa bf16 [B*16,2048,64].
// MODE 2: rope -> Ka bf16 [B*4,2048,64].  MODE 3: V^T bf16 [B*4,64,2048].
template<int MODE, typename TA>
__device__ __forceinline__ void gemm_bt_body(
    short* As, short* Bs, void* __restrict__ Cout,
    const TA* __restrict__ A, const float* __restrict__ B,
    const float* __restrict__ bias, const float* __restrict__ tab,
    int ntile, int M, int N, int K)
{
  constexpr int BK = 32, LDT = 40;  // 80B rows: 16B aligned, 2-way banks (free)
  const int n0 = ntile * 128, m0 = blockIdx.y * 128;
  const int tid = threadIdx.x;
  const int w = tid >> 6, lane = tid & 63;
  const int wm = w >> 1, wn = w & 1;
  const int lr = lane & 15, lk = (lane >> 4) * 8;
  f32x4 acc[4][4] = {};
  for (int k0 = 0; k0 < K; k0 += BK){
    __syncthreads();
    {
      const int r = tid >> 2, c8 = (tid & 3) * 8;
      *reinterpret_cast<short8*>(&As[ r      * LDT + c8]) = load8(A + (size_t)(m0 + r     ) * K + k0 + c8);
      *reinterpret_cast<short8*>(&As[(r + 64)* LDT + c8]) = load8(A + (size_t)(m0 + r + 64) * K + k0 + c8);
      *reinterpret_cast<short8*>(&Bs[ r      * LDT + c8]) = load8(B + (size_t)(n0 + r     ) * K + k0 + c8);
      *reinterpret_cast<short8*>(&Bs[(r + 64)* LDT + c8]) = load8(B + (size_t)(n0 + r + 64) * K + k0 + c8);
    }
    __syncthreads();
    short8 af[4], bfm[4];
    #pragma unroll
    for (int mt = 0; mt < 4; mt++)
      af[mt] = *reinterpret_cast<short8*>(&As[(wm*64 + mt*16 + lr) * LDT + lk]);
    #pragma unroll
    for (int nt = 0; nt < 4; nt++)
      bfm[nt] = *reinterpret_cast<short8*>(&Bs[(wn*64 + nt*16 + lr) * LDT + lk]);
    #pragma unroll
    for (int mt = 0; mt < 4; mt++)
      #pragma unroll
      for (int nt = 0; nt < 4; nt++)
        acc[mt][nt] = __builtin_amdgcn_mfma_f32_16x16x32_bf16(af[mt], bfm[nt], acc[mt][nt], 0, 0, 0);
  }
  const int lg = lane >> 4;
  if constexpr (MODE == 0){
    float* C = (float*)Cout;
    #pragma unroll
    for (int mt = 0; mt < 4; mt++){
      #pragma unroll
      for (int nt = 0; nt < 4; nt++){
        const int col = n0 + wn*64 + nt*16 + lr;
        const float bv = bias[col];
        const int rbase = m0 + wm*64 + mt*16 + lg*4;
        #pragma unroll
        for (int i = 0; i < 4; i++)
          C[(size_t)(rbase + i) * N + col] = acc[mt][nt][i] + bv;
      }
    }
  } else if constexpr (MODE == 1 || MODE == 2){
    bf16* dst = (bf16*)Cout;
    constexpr int NH = (MODE == 1) ? 16 : 4;
    // SC folds attention scale + log2(e) into Q so softmax runs in exp2 domain
    constexpr float SC = (MODE == 1) ? 0.18033688011112042f : 1.0f;
    #pragma unroll
    for (int mt = 0; mt < 4; mt++){
      #pragma unroll
      for (int nt = 0; nt < 2; nt++){
        const int col = n0 + wn*64 + nt*16 + lr;
        const int d = col & 63;        // 0..31
        const int hh = col >> 6;
        const float b1 = bias[col], b2 = bias[col + 32];
        #pragma unroll
        for (int i = 0; i < 4; i++){
          const int m = m0 + wm*64 + mt*16 + lg*4 + i;
          const int s = m & 2047, bb = m >> 11;
          const float cs = tab[(s*32 + d)*2], sn = tab[(s*32 + d)*2 + 1];
          const float x1 = acc[mt][nt][i] + b1;
          const float x2 = acc[mt][nt+2][i] + b2;
          const size_t o = ((size_t)(bb*NH + hh) * 2048 + s) * 64 + d;
          dst[o]      = __float2bfloat16((x1*cs - x2*sn) * SC);
          dst[o + 32] = __float2bfloat16((x2*cs + x1*sn) * SC);
        }
      }
    }
  } else {  // MODE 3: V^T
    bf16* dst = (bf16*)Cout;
    #pragma unroll
    for (int mt = 0; mt < 4; mt++){
      #pragma unroll
      for (int nt = 0; nt < 4; nt++){
        const int col = n0 + wn*64 + nt*16 + lr;
        const int kv = col >> 6, d = col & 63;
        const float bv = bias[col];
        #pragma unroll
        for (int i = 0; i < 4; i++){
          const int m = m0 + wm*64 + mt*16 + lg*4 + i;
          const int s = m & 2047, bb = m >> 11;
          dst[((size_t)(bb*4 + kv) * 64 + d) * 2048 + s] = __float2bfloat16(acc[mt][nt][i] + bv);
        }
      }
    }
  }
}

// Merged QKV projection: x 0-7 Q tiles, 8-9 K tiles, 10-11 V tiles.
__global__ __launch_bounds__(256) void gemm_qkv_kernel(
    bf16* Qa, bf16* Ka, bf16* Va,
    const float* query, const float* key, const float* value,
    const float* Wq, const float* bq, const float* Wk, const float* bk,
    const float* Wv, const float* bv, const float* tab){
  __shared__ short As[128*40], Bs[128*40];
  const int x = blockIdx.x;
  if (x < 8)
    gemm_bt_body<1, float>(As, Bs, Qa, query, Wq, bq, tab, x,    4096, 1024, 1024);
  else if (x < 10)
    gemm_bt_body<2, float>(As, Bs, Ka, key,   Wk, bk, tab, x-8,  4096, 256, 1024);
  else
    gemm_bt_body<3, float>(As, Bs, Va, value, Wv, bv, tab, x-10, 4096, 256, 1024);
}
__global__ __launch_bounds__(256) void gemm_out_kernel(
    float* C, const bf16* A, const float* B, const float* bias){
  __shared__ short As[128*40], Bs[128*40];
  gemm_bt_body<0, bf16>(As, Bs, C, A, B, bias, nullptr, blockIdx.x, 4096, 1024, 1024);
}

// Flash attention v5: grid (16, 32); 4 waves x 32 q-rows, KV tiles of 64.
// Swapped QK^T; P in registers (permuted-k PV); K/V staged by global_load_lds
// with pre-swizzled per-lane SOURCE (linear LDS dest, XOR-swizzled reads);
// lane-local softmax (cross-lane reduce deferred to epilogue); dbuf, 1 barrier/tile.
__global__ __launch_bounds__(256) void attn_kernel(
    bf16* __restrict__ ctx, const bf16* __restrict__ Qa,
    const bf16* __restrict__ Ka, const bf16* __restrict__ Vt)
{
  __shared__ short Klds[2][64 * 64];
  __shared__ short Vlds[2][64 * 64];
  const int bh = blockIdx.y, b = bh >> 4, h = bh & 15, kvh = h >> 2;
  const int q0 = blockIdx.x * 128;
  const int tid = threadIdx.x, w = tid >> 6, lane = tid & 63;
  const int lr = lane & 15, lg = lane >> 4;
  const bf16* Qbase = Qa + (size_t)bh * 2048 * 64;
  const bf16* Kbase = Ka + (size_t)(b*4 + kvh) * 2048 * 64;
  const bf16* Vbase = Vt + (size_t)(b*4 + kvh) * 64 * 2048;

  short8 qf[2][2];
  #pragma unroll
  for (int qt = 0; qt < 2; qt++){
    qf[qt][0] = load8(Qbase + (size_t)(q0 + w*32 + qt*16 + lr) * 64 + lg*8);
    qf[qt][1] = load8(Qbase + (size_t)(q0 + w*32 + qt*16 + lr) * 64 + 32 + lg*8);
  }

  // staging: wave w covers rows w*16..w*16+15 (two 8-row DMA chunks).
  // LDS dest is linear; global source column pre-swizzled so that the
  // read-side XOR swizzle sees the right data: chunk = (lane&7)^(lane>>3).
  const int l8 = lane >> 3;
  const int ch = (lane & 7) ^ l8;
  const bf16* kSrc = Kbase + (size_t)(w*16 + l8) * 64 + ch*8;
  const bf16* vSrc = Vbase + (size_t)(w*16 + l8) * 2048 + ch*8;
  short* Kd0 = &Klds[0][(w*16) * 64];
  short* Vd0 = &Vlds[0][(w*16) * 64];
  auto stage = [&](int t){
    const int bo = (t & 1) * 64*64;
    const bf16* ks = kSrc + (size_t)t * 64 * 64;
    const bf16* vs = vSrc + t * 64;
    gload16(ks,            Kd0 + bo);
    gload16(ks + 8*64,     Kd0 + bo + 8*64);
    gload16(vs,            Vd0 + bo);
    gload16(vs + 8*2048,   Vd0 + bo + 8*64);
  };
  stage(0);

  float mrow[2] = {-1e30f, -1e30f}, lsum[2] = {0.f, 0.f};
  f32x4 o[2][4] = {};

  // byte-offset swizzle for row-major [64][64] bf16 (128B rows)
  auto swzb = [](int row, int cb) -> int { return row*128 + (cb ^ ((row & 7) << 4)); };

  for (int t = 0; t < 32; t++){
    char* Kc = (char*)&Klds[t & 1][0];
    char* Vc = (char*)&Vlds[t & 1][0];
    __syncthreads();                 // drains this wave's DMA; tile t ready
    if (t < 31) stage(t + 1);        // issue next tile into other buffer

    // S^T = K x Q : lane holds S2[kv=mt*16+lg*4+i][q = qt*16+lr] (exp2 domain)
    f32x4 st[4][2] = {};
    __builtin_amdgcn_s_setprio(1);
    #pragma unroll
    for (int mt = 0; mt < 4; mt++){
      #pragma unroll
      for (int kk = 0; kk < 2; kk++){
        short8 kf = *reinterpret_cast<const short8*>(Kc + swzb(mt*16 + lr, kk*64 + lg*16));
        #pragma unroll
        for (int qt = 0; qt < 2; qt++)
          st[mt][qt] = __builtin_amdgcn_mfma_f32_16x16x32_bf16(kf, qf[qt][kk], st[mt][qt], 0, 0, 0);
      }
    }
    __builtin_amdgcn_s_setprio(0);

    // lane-local softmax; cross-lane work only on (rare) rescale
    short8 pf[2][2];
    #pragma unroll
    for (int qt = 0; qt < 2; qt++){
      float mx = st[0][qt][0];
      #pragma unroll
      for (int mt = 0; mt < 4; mt++)
        #pragma unroll
        for (int i = 0; i < 4; i++)
          mx = fmaxf(mx, st[mt][qt][i]);
      if (__any(mx > mrow[qt] + 8.0f)){
        mx = fmaxf(mx, __shfl_xor(mx, 16));
        mx = fmaxf(mx, __shfl_xor(mx, 32));
        const float nm = fmaxf(mrow[qt], mx);
        const float alpha = exp2f(mrow[qt] - nm);
        mrow[qt] = nm;
        lsum[qt] *= alpha;
        float ab[4];
        #pragma unroll
        for (int i = 0; i < 4; i++) ab[i] = __shfl(alpha, lg*4 + i);
        #pragma unroll
        for (int dt = 0; dt < 4; dt++)
          #pragma unroll
          for (int i = 0; i < 4; i++)
            o[qt][dt][i] *= ab[i];
      }
      // P packed in natural slot order (defines k-permutation):
      // pf[qt][kkA] slot j = P[q][kv = 32*kkA + 16*(j>>2) + 4*lg + (j&3)]
      float s = 0.f;
      #pragma unroll
      for (int mt = 0; mt < 4; mt++)
        #pragma unroll
        for (int i = 0; i < 4; i++){
          const float e = exp2f(st[mt][qt][i] - mrow[qt]);
          s += e;
          pf[qt][mt >> 1][(mt & 1)*4 + i] = f2bf(e);
        }
      lsum[qt] += s;   // lane-partial; reduced in epilogue
    }

    // PV with matching permuted V B-frag: two b64 runs per 32-chunk
    __builtin_amdgcn_s_setprio(1);
    #pragma unroll
    for (int dt = 0; dt < 4; dt++){
      #pragma unroll
      for (int kkA = 0; kkA < 2; kkA++){
        short4v vlo = *reinterpret_cast<const short4v*>(Vc + swzb(dt*16 + lr, kkA*64 + lg*8));
        short4v vhi = *reinterpret_cast<const short4v*>(Vc + swzb(dt*16 + lr, kkA*64 + lg*8 + 32));
        short8 vf;
        vf[0]=vlo[0]; vf[1]=vlo[1]; vf[2]=vlo[2]; vf[3]=vlo[3];
        vf[4]=vhi[0]; vf[5]=vhi[1]; vf[6]=vhi[2]; vf[7]=vhi[3];
        #pragma unroll
        for (int qt = 0; qt < 2; qt++)
          o[qt][dt] = __builtin_amdgcn_mfma_f32_16x16x32_bf16(pf[qt][kkA], vf, o[qt][dt], 0, 0, 0);
      }
    }
    __builtin_amdgcn_s_setprio(0);
  }

  #pragma unroll
  for (int qt = 0; qt < 2; qt++){
    float s = lsum[qt];
    s += __shfl_xor(s, 16);
    s += __shfl_xor(s, 32);
    float lb[4];
    #pragma unroll
    for (int i = 0; i < 4; i++) lb[i] = 1.0f / __shfl(s, lg*4 + i);
    #pragma unroll
    for (int dt = 0; dt < 4; dt++){
      #pragma unroll
      for (int i = 0; i < 4; i++){
        const int q = q0 + w*32 + qt*16 + lg*4 + i;
        ctx[(size_t)(b*2048 + q) * 1024 + h*64 + dt*16 + lr] =
            __float2bfloat16(o[qt][dt][i] * lb[i]);
      }
    }
  }
}

extern "C" void kernel_launch(void* const* d_in, const int* in_sizes, int n_in,
                              void* d_out, int out_size, void* d_ws, size_t ws_size,
                              hipStream_t stream)
{
  const float* query = (const float*)d_in[0];
  const float* key   = (const float*)d_in[1];
  const float* value = (const float*)d_in[2];
  const float* Wq = (const float*)d_in[3];
  const float* bq = (const float*)d_in[4];
  const float* Wk = (const float*)d_in[5];
  const float* bk = (const float*)d_in[6];
  const float* Wv = (const float*)d_in[7];
  const float* bv = (const float*)d_in[8];
  const float* Wo = (const float*)d_in[9];
  const float* bo = (const float*)d_in[10];
  float* out = (float*)d_out;

  char* ws = (char*)d_ws;
  size_t off = 0;
  float* tab = (float*)(ws + off); off += (size_t)2048 * 32 * 2 * 4;   // cos/sin
  bf16*  Qa  = (bf16*)(ws + off);  off += (size_t)32 * 2048 * 64 * 2;  // [B*16,S,64]
  bf16*  Ka  = (bf16*)(ws + off);  off += (size_t)8 * 2048 * 64 * 2;   // [B*4,S,64]
  bf16*  Va  = (bf16*)(ws + off);  off += (size_t)8 * 64 * 2048 * 2;   // [B*4,64,S]
  bf16*  ctx = (bf16*)(ws + off);  off += (size_t)2 * 2048 * 1024 * 2; // [B,S,1024]

  rope_table_kernel<<<256, 256, 0, stream>>>(tab);
  gemm_qkv_kernel<<<dim3(12, 32), 256, 0, stream>>>(Qa, Ka, Va, query, key, value,
                                                    Wq, bq, Wk, bk, Wv, bv, tab);
  attn_kernel<<<dim3(16, 32), 256, 0, stream>>>(ctx, Qa, Ka, Va);
  gemm_out_kernel<<<dim3(8, 32), 256, 0, stream>>>(out, ctx, Wo, bo);
}